// Round 13
// baseline (175.809 us; speedup 1.0000x reference)
//
#include <hip/hip_runtime.h>

#define B_ 8
#define C_ 3
#define H_ 256
#define W_ 256
#define HID_ 32
#define HW_ (H_*W_)            // 65536
#define N_ (B_*H_*W_)          // 524288
#define K01_ 0xBDCCCCCDu       // fkey(0.1f)
#define TILE_ 16

// XCD-chunked swizzle for 2048-block grids: consecutive hardware block ids
// round-robin across 8 XCDs; remap so XCD x owns image x -> region atomics
// and chase reads stay in one L2.
__device__ __forceinline__ int swz2048(int bid){ return ((bid & 7) << 8) | (bid >> 3); }

__device__ __forceinline__ unsigned fkey(float f){
  unsigned u = __float_as_uint(f);
  return (u & 0x80000000u) ? ~u : (u | 0x80000000u);
}

// mk entry: [63:56]=tag(it+1) | [55:24]=fkey(sim) | [23:0]=neighbor id (N<2^24).
// atomicMax: newer tag always wins; same tag -> (key,id) lexicographic max,
// which is exactly the reference's "max rb among sim==maxsim" tie-break.
__device__ __forceinline__ unsigned long long pack_mk(unsigned tag, unsigned key, int id){
  return ((unsigned long long)tag << 56) | ((unsigned long long)key << 24) | (unsigned)id;
}

__device__ __forceinline__ int parent_dec(unsigned long long m, unsigned tag, int x){
  if ((unsigned)(m >> 56) != tag) return x;
  return ((unsigned)(m >> 24) > K01_) ? (int)(m & 0xFFFFFFu) : x;
}

// 16x16-tile conv + init + it0 in-tile sims (img tile in LDS; sims via wave
// shuffles; lane layout r = wv*4 + (lane>>4), c = lane&15).
// Weights/bias are read DIRECTLY from global with wave-uniform indices ->
// compiler emits scalar s_load broadcasts (K$), zero LDS traffic for weights,
// and the fmaf chain (t=0..26) keeps the exact accumulation order.
// Also clears mk[i] (all in-tile mk atomics stay in this block; cross-tile
// edges run later in k_bedge). labels is NOT written here (upd0 derives l=i).
__global__ __launch_bounds__(256) void k_conv_init(const float* __restrict__ img,
    const float* __restrict__ cw, const float* __restrict__ cb,
    float* __restrict__ fsum, float* __restrict__ cnt, float* __restrict__ psum,
    unsigned long long* __restrict__ mk, int* __restrict__ mflag){
  __shared__ float img_s[C_][TILE_+2][TILE_+3];   // 3 x 18 x 19
  __shared__ float rowbuf[3*TILE_][33];           // rows 4,8,12 cross-wave
  if (blockIdx.x == 0 && threadIdx.x < 16) mflag[threadIdx.x] = 0;

  int sb = swz2048(blockIdx.x);
  int b  = sb >> 8;
  int ti = sb & 255;
  int h0 = (ti >> 4) * TILE_;
  int w0 = (ti & 15) * TILE_;

  int lane = threadIdx.x & 63, wv = threadIdx.x >> 6;
  int r = wv*4 + (lane >> 4);
  int c = lane & 15;
  int h = h0 + r, w = w0 + c;
  int i = (b << 16) | (h << 8) | w;

  mk[i] = 0ULL;                      // clear before this block's atomics (sync below)

  // stage img tile (18x18x3) with zero padding
  for (int t = threadIdx.x; t < C_*18*18; t += blockDim.x){
    int ci = t / 324; int rm = t - ci*324; int rr = rm / 18; int cc = rm - rr*18;
    int hh = h0 - 1 + rr, ww = w0 - 1 + cc;
    float v = 0.f;
    if (hh >= 0 && hh < H_ && ww >= 0 && ww < W_)
      v = img[(size_t)(b*C_+ci)*HW_ + hh*W_ + ww];
    img_s[ci][rr][cc] = v;
  }
  __syncthreads();

  float patch[27];
  #pragma unroll
  for (int ci=0; ci<C_; ++ci)
    #pragma unroll
    for (int kh=0; kh<3; ++kh)
      #pragma unroll
      for (int kw=0; kw<3; ++kw)
        patch[ci*9+kh*3+kw] = img_s[ci][r+kh][c+kw];

  float acc[HID_];
  #pragma unroll 4
  for (int oc=0; oc<HID_; ++oc){
    float a = cb[oc];                         // uniform -> scalar load
    const float* wp = cw + oc*27;             // uniform indices -> s_load
    #pragma unroll
    for (int t=0; t<27; ++t) a = fmaf(patch[t], wp[t], a);
    acc[oc] = a;
  }

  {
    float4* o4 = (float4*)(fsum + (size_t)i*HID_);
    #pragma unroll
    for (int k=0; k<HID_/4; ++k)
      o4[k] = make_float4(acc[4*k], acc[4*k+1], acc[4*k+2], acc[4*k+3]);
  }
  cnt[i] = 1.0f;
  #pragma unroll
  for (int cc=0; cc<C_; ++cc) psum[(size_t)i*C_+cc] = img_s[cc][r+1][c+1];

  // stage rows 4,8,12 (each wave's lanes 0..15) for cross-wave down edges
  if (wv >= 1 && lane < 16){
    float* dst = rowbuf[(wv-1)*TILE_ + c];
    #pragma unroll
    for (int d=0; d<HID_; ++d) dst[d] = acc[d];
  }

  float d2R = 0.f;
  #pragma unroll
  for (int k=0; k<HID_/4; ++k){
    float t0 = acc[4*k]   - __shfl_down(acc[4*k],  1);
    float t1 = acc[4*k+1] - __shfl_down(acc[4*k+1],1);
    float t2 = acc[4*k+2] - __shfl_down(acc[4*k+2],1);
    float t3 = acc[4*k+3] - __shfl_down(acc[4*k+3],1);
    d2R += t0*t0 + t1*t1 + t2*t2 + t3*t3;
  }
  float d2D = 0.f;
  #pragma unroll
  for (int k=0; k<HID_/4; ++k){
    float t0 = acc[4*k]   - __shfl_down(acc[4*k],  16);
    float t1 = acc[4*k+1] - __shfl_down(acc[4*k+1],16);
    float t2 = acc[4*k+2] - __shfl_down(acc[4*k+2],16);
    float t3 = acc[4*k+3] - __shfl_down(acc[4*k+3],16);
    d2D += t0*t0 + t1*t1 + t2*t2 + t3*t3;
  }
  __syncthreads();
  if (lane >= 48 && wv < 3){          // row 4wv+3: neighbor row in wave wv+1
    const float* nb = rowbuf[wv*TILE_ + c];
    d2D = 0.f;
    #pragma unroll
    for (int k=0; k<HID_/4; ++k){
      float t0 = acc[4*k]   - nb[4*k];
      float t1 = acc[4*k+1] - nb[4*k+1];
      float t2 = acc[4*k+2] - nb[4*k+2];
      float t3 = acc[4*k+3] - nb[4*k+3];
      d2D += t0*t0 + t1*t1 + t2*t2 + t3*t3;
    }
  }

  if (c < TILE_-1){
    unsigned key = fkey(expf(-d2R));
    atomicMax(mk+i,   pack_mk(1u, key, i+1));
    atomicMax(mk+i+1, pack_mk(1u, key, i));
  }
  if (r < TILE_-1){
    unsigned key = fkey(expf(-d2D));
    atomicMax(mk+i,     pack_mk(1u, key, i+W_));
    atomicMax(mk+i+W_,  pack_mk(1u, key, i));
  }
}

// cross-tile it0 edges: 8 images x {15 boundary cols x 256, 15 boundary rows x 256}
__global__ void k_bedge(const float* __restrict__ fsum,
                        unsigned long long* __restrict__ mk){
  int t = blockIdx.x*blockDim.x + threadIdx.x;
  if (t >= B_*2*15*256) return;
  int y  = t & 255;
  int k  = (t >> 8) % 15;
  int ty = (t >> 8) / 15;
  int b  = ty >> 1, tp = ty & 1;
  int i, j;
  if (tp == 0){ i = (b<<16) | (y<<8) | (16*k+15); j = i+1;  }
  else        { i = (b<<16) | ((16*k+15)<<8) | y; j = i+W_; }
  const float4* fa = (const float4*)(fsum + (size_t)i*HID_);
  const float4* fb = (const float4*)(fsum + (size_t)j*HID_);
  float d2 = 0.f;
  #pragma unroll
  for (int q=0; q<HID_/4; ++q){
    float4 va = fa[q], vb = fb[q];
    float t0 = va.x-vb.x, t1 = va.y-vb.y, t2 = va.z-vb.z, t3 = va.w-vb.w;
    d2 += t0*t0 + t1*t1 + t2*t2 + t3*t3;
  }
  unsigned key = fkey(expf(-d2));
  atomicMax(mk+i, pack_mk(1u, key, j));
  atomicMax(mk+j, pack_mk(1u, key, i));
}

// mid-iteration fused sim+best, 1 px/thread, XCD-swizzled. Corner dedup:
// when right and down edges lead to the SAME neighbor region, the sim/key
// and atomics are identical -> compute once.
__global__ void k_simbest(const int* __restrict__ labels,
                          const float* __restrict__ fsum, const float* __restrict__ cnt,
                          unsigned long long* __restrict__ mk, unsigned tag,
                          const int* __restrict__ mflag){
  if (mflag[tag-1] == 0) return;     // tag>=2 always (loop starts at it=1)
  int i = swz2048(blockIdx.x)*256 + threadIdx.x;
  int rem = i & (HW_-1); int h = rem >> 8; int w = rem & (W_-1);
  int ri = labels[i];
  int rR = (w < W_-1) ? labels[i+1]  : ri;
  int rD = (h < H_-1) ? labels[i+W_] : ri;
  bool eR = (rR != ri), eD = (rD != ri) && (rD != rR);   // dedup corner case
  if (!eR && !eD) return;
  float rci = 1.0f / cnt[ri];
  const float4* fi = (const float4*)(fsum + (size_t)ri*HID_);
  float4 mi[HID_/4];
  #pragma unroll
  for (int k=0; k<HID_/4; ++k){
    float4 v = fi[k];
    mi[k] = make_float4(v.x*rci, v.y*rci, v.z*rci, v.w*rci);
  }
  if (eR){
    float rcj = 1.0f / cnt[rR];
    const float4* fj = (const float4*)(fsum + (size_t)rR*HID_);
    float d2 = 0.f;
    #pragma unroll
    for (int k=0; k<HID_/4; ++k){
      float4 v = fj[k];
      float tx = mi[k].x - v.x*rcj; float ty = mi[k].y - v.y*rcj;
      float tz = mi[k].z - v.z*rcj; float tw = mi[k].w - v.w*rcj;
      d2 += tx*tx + ty*ty + tz*tz + tw*tw;
    }
    unsigned key = fkey(expf(-d2));
    atomicMax(mk+ri, pack_mk(tag, key, rR));
    atomicMax(mk+rR, pack_mk(tag, key, ri));
  }
  if (eD){
    float rcj = 1.0f / cnt[rD];
    const float4* fj = (const float4*)(fsum + (size_t)rD*HID_);
    float d2 = 0.f;
    #pragma unroll
    for (int k=0; k<HID_/4; ++k){
      float4 v = fj[k];
      float tx = mi[k].x - v.x*rcj; float ty = mi[k].y - v.y*rcj;
      float tz = mi[k].z - v.z*rcj; float tw = mi[k].w - v.w*rcj;
      d2 += tx*tx + ty*ty + tz*tz + tw*tw;
    }
    unsigned key = fkey(expf(-d2));
    atomicMax(mk+ri, pack_mk(tag, key, rD));
    atomicMax(mk+rD, pack_mk(tag, key, ri));
  }
}

// chase + fold + relabel, 1 px/thread, XCD-swizzled. first=1 (it0): labels
// is not yet initialized, l==i by construction. Sets mflag[tag] on any fold;
// exits early when previous iteration was merge-free.
__global__ void k_update(const unsigned long long* __restrict__ mk, unsigned tag,
                         int* __restrict__ labels,
                         float* __restrict__ fsum, float* __restrict__ psum,
                         float* __restrict__ cnt, int* __restrict__ mflag,
                         int first){
  if (tag >= 2 && mflag[tag-1] == 0) return;
  int i = swz2048(blockIdx.x)*256 + threadIdx.x;
  int l = first ? i : labels[i];
  int x = l;
  for (int it = 0; it < (1<<20); ++it){
    int p = parent_dec(mk[x], tag, x);
    if (p == x) break;
    int pp = parent_dec(mk[p], tag, p);
    if (pp == x && x < p) break;     // broken 2-cycle: x is the root
    x = p;
  }
  if (l == i && x != i){             // dying root: fold into surviving root
    mflag[tag] = 1;
    atomicAdd(cnt+x, cnt[i]);
    const float* s = fsum + (size_t)i*HID_;
    float* ds = fsum + (size_t)x*HID_;
    #pragma unroll
    for (int d=0; d<HID_; ++d) atomicAdd(ds+d, s[d]);
    const float* ps = psum + (size_t)i*C_;
    float* dp = psum + (size_t)x*C_;
    #pragma unroll
    for (int cc=0; cc<C_; ++cc) atomicAdd(dp+cc, ps[cc]);
  }
  labels[i] = x;
}

// region features at roots only: rf3[l] = Linear(fsum[l]/cnt) - psum[l]/cnt,
// padded to float4 so k_out gathers one dwordx4. Every value l appearing in
// labels satisfies labels[l]==l, so all needed slots are written.
__global__ __launch_bounds__(256) void k_rf3(const int* __restrict__ labels,
      const float* __restrict__ cnt, const float* __restrict__ fsum,
      const float* __restrict__ psum, const float* __restrict__ lw,
      const float* __restrict__ lb, float4* __restrict__ rf3){
  __shared__ float lw_s[C_*HID_];
  __shared__ float lb_s[C_];
  for (int t = threadIdx.x; t < C_*HID_; t += blockDim.x) lw_s[t] = lw[t];
  if (threadIdx.x < C_) lb_s[threadIdx.x] = lb[threadIdx.x];
  __syncthreads();
  int i = swz2048(blockIdx.x)*256 + threadIdx.x;
  if (labels[i] != i) return;        // roots only
  float rc = 1.0f / cnt[i];
  const float* s = fsum + (size_t)i*HID_;
  float rf[C_];
  #pragma unroll
  for (int cc=0; cc<C_; ++cc){
    float a = 0.f;
    const float* wv = lw_s + cc*HID_;
    #pragma unroll
    for (int d=0; d<HID_; ++d) a += (s[d]*rc)*wv[d];
    rf[cc] = (a + lb_s[cc]) - psum[(size_t)i*C_+cc]*rc;
  }
  rf3[i] = make_float4(rf[0], rf[1], rf[2], 0.f);
}

// finalize: one 16B rf3 gather per pixel (wave-broadcast for uniform regions),
// mean injection, labels as float.
__global__ __launch_bounds__(256) void k_out(const int* __restrict__ labels,
      const float* __restrict__ img, const float4* __restrict__ rf3,
      float* __restrict__ out, float* __restrict__ outlab){
  int i = swz2048(blockIdx.x)*256 + threadIdx.x;
  int l = labels[i];
  float4 rf = rf3[l];
  int b = i >> 16; int rem = i & (HW_-1);
  const float* ip = img + (size_t)b*C_*HW_ + rem;
  out[(size_t)i*C_+0] = ip[0]             + rf.x;
  out[(size_t)i*C_+1] = ip[(size_t)HW_]   + rf.y;
  out[(size_t)i*C_+2] = ip[(size_t)2*HW_] + rf.z;
  outlab[i] = (float)l;
}

extern "C" void kernel_launch(void* const* d_in, const int* in_sizes, int n_in,
                              void* d_out, int out_size, void* d_ws, size_t ws_size,
                              hipStream_t stream) {
  const float* img = (const float*)d_in[0];
  const float* cw  = (const float*)d_in[1];
  const float* cb  = (const float*)d_in[2];
  const float* lw  = (const float*)d_in[3];
  const float* lb  = (const float*)d_in[4];

  char* ws = (char*)d_ws;
  size_t off = 0;
  auto alloc = [&](size_t bytes) -> void* {
    void* p = ws + off; off += (bytes + 255) & ~(size_t)255; return p;
  };
  float*              fsum   = (float*)              alloc((size_t)N_*HID_*4);
  float*              psum   = (float*)              alloc((size_t)N_*C_*4);
  float*              cnt    = (float*)              alloc((size_t)N_*4);
  unsigned long long* mk     = (unsigned long long*) alloc((size_t)N_*8);
  int*                labels = (int*)                alloc((size_t)N_*4);
  float4*             rf3    = (float4*)             alloc((size_t)N_*16);
  int*                mflag  = (int*)                alloc(64);

  dim3 blk(256);
  const int gN = 2048;

  k_conv_init<<<gN, blk, 0, stream>>>(img, cw, cb, fsum, cnt, psum, mk, mflag);
  k_bedge<<<240, blk, 0, stream>>>(fsum, mk);
  k_update<<<gN, blk, 0, stream>>>(mk, 1u, labels, fsum, psum, cnt, mflag, 1);

  for (int it = 1; it < 8; ++it) {
    k_simbest<<<gN, blk, 0, stream>>>(labels, fsum, cnt, mk, (unsigned)(it+1), mflag);
    k_update<<<gN, blk, 0, stream>>>(mk, (unsigned)(it+1), labels, fsum, psum, cnt, mflag, 0);
  }

  k_rf3<<<gN, blk, 0, stream>>>(labels, cnt, fsum, psum, lw, lb, rf3);

  float* out = (float*)d_out;
  k_out<<<gN, blk, 0, stream>>>(labels, img, rf3, out, out + (size_t)N_*C_);
}

// Round 14
// 169.718 us; speedup vs baseline: 1.0359x; 1.0359x over previous
//
#include <hip/hip_runtime.h>

#define B_ 8
#define C_ 3
#define H_ 256
#define W_ 256
#define HID_ 32
#define HW_ (H_*W_)            // 65536
#define N_ (B_*H_*W_)          // 524288
#define K01_ 0xBDCCCCCDu       // fkey(0.1f)
#define TILE_ 16

// XCD-chunked swizzle for 2048-block grids: consecutive hardware block ids
// round-robin across 8 XCDs; remap so XCD x owns image x -> region atomics
// and chase reads stay in one L2.
__device__ __forceinline__ int swz2048(int bid){ return ((bid & 7) << 8) | (bid >> 3); }

__device__ __forceinline__ unsigned fkey(float f){
  unsigned u = __float_as_uint(f);
  return (u & 0x80000000u) ? ~u : (u | 0x80000000u);
}

// mk entry: [63:56]=tag(it+1) | [55:24]=fkey(sim) | [23:0]=neighbor id (N<2^24).
// atomicMax: newer tag always wins; same tag -> (key,id) lexicographic max,
// which is exactly the reference's "max rb among sim==maxsim" tie-break.
__device__ __forceinline__ unsigned long long pack_mk(unsigned tag, unsigned key, int id){
  return ((unsigned long long)tag << 56) | ((unsigned long long)key << 24) | (unsigned)id;
}

__device__ __forceinline__ int parent_dec(unsigned long long m, unsigned tag, int x){
  if ((unsigned)(m >> 56) != tag) return x;
  return ((unsigned)(m >> 24) > K01_) ? (int)(m & 0xFFFFFFu) : x;
}

// 16x16-tile conv + init + it0 in-tile sims (img tile in LDS, sims via wave
// shuffles; lane layout r = wv*4 + (lane>>4), c = lane&15). Weights padded to
// [32][28], read as 7 float4 LDS broadcasts per oc (R12's proven-best form);
// fmaf chain keeps exact accumulation order. Clears mk[i] (all in-tile mk
// atomics stay in this block; cross-tile edges later in k_bedge). labels is
// NOT written here (upd0 derives l=i via the first flag).
__global__ __launch_bounds__(256) void k_conv_init(const float* __restrict__ img,
    const float* __restrict__ cw, const float* __restrict__ cb,
    float* __restrict__ fsum, float* __restrict__ cnt, float* __restrict__ psum,
    unsigned long long* __restrict__ mk, int* __restrict__ mflag){
  __shared__ __align__(16) float w_s[HID_][28];   // 27 weights + zero pad
  __shared__ float b_s[HID_];
  __shared__ float img_s[C_][TILE_+2][TILE_+3];   // 3 x 18 x 19
  __shared__ float rowbuf[3*TILE_][33];           // rows 4,8,12 cross-wave
  for (int t = threadIdx.x; t < HID_*28; t += blockDim.x){
    int oc = t / 28, e = t - oc*28;
    w_s[oc][e] = (e < 27) ? cw[oc*27 + e] : 0.f;
  }
  if (threadIdx.x < HID_) b_s[threadIdx.x] = cb[threadIdx.x];
  if (blockIdx.x == 0 && threadIdx.x < 16) mflag[threadIdx.x] = 0;

  int sb = swz2048(blockIdx.x);
  int b  = sb >> 8;
  int ti = sb & 255;
  int h0 = (ti >> 4) * TILE_;
  int w0 = (ti & 15) * TILE_;

  int lane = threadIdx.x & 63, wv = threadIdx.x >> 6;
  int r = wv*4 + (lane >> 4);
  int c = lane & 15;
  int h = h0 + r, w = w0 + c;
  int i = (b << 16) | (h << 8) | w;

  mk[i] = 0ULL;                      // clear before this block's atomics (sync below)

  // stage img tile (18x18x3) with zero padding
  for (int t = threadIdx.x; t < C_*18*18; t += blockDim.x){
    int ci = t / 324; int rm = t - ci*324; int rr = rm / 18; int cc = rm - rr*18;
    int hh = h0 - 1 + rr, ww = w0 - 1 + cc;
    float v = 0.f;
    if (hh >= 0 && hh < H_ && ww >= 0 && ww < W_)
      v = img[(size_t)(b*C_+ci)*HW_ + hh*W_ + ww];
    img_s[ci][rr][cc] = v;
  }
  __syncthreads();

  float patch[28];
  #pragma unroll
  for (int ci=0; ci<C_; ++ci)
    #pragma unroll
    for (int kh=0; kh<3; ++kh)
      #pragma unroll
      for (int kw=0; kw<3; ++kw)
        patch[ci*9+kh*3+kw] = img_s[ci][r+kh][c+kw];
  patch[27] = 0.f;

  float acc[HID_];
  #pragma unroll 4
  for (int oc=0; oc<HID_; ++oc){
    float a = b_s[oc];
    const float4* w4 = (const float4*)(&w_s[oc][0]);
    #pragma unroll
    for (int k7=0; k7<7; ++k7){
      float4 wv4 = w4[k7];                 // LDS broadcast, 1 instr / 4 weights
      a = fmaf(patch[k7*4+0], wv4.x, a);
      a = fmaf(patch[k7*4+1], wv4.y, a);
      a = fmaf(patch[k7*4+2], wv4.z, a);
      a = fmaf(patch[k7*4+3], wv4.w, a);
    }
    acc[oc] = a;
  }

  {
    float4* o4 = (float4*)(fsum + (size_t)i*HID_);
    #pragma unroll
    for (int k=0; k<HID_/4; ++k)
      o4[k] = make_float4(acc[4*k], acc[4*k+1], acc[4*k+2], acc[4*k+3]);
  }
  cnt[i] = 1.0f;
  #pragma unroll
  for (int cc=0; cc<C_; ++cc) psum[(size_t)i*C_+cc] = img_s[cc][r+1][c+1];

  // stage rows 4,8,12 (each wave's lanes 0..15) for cross-wave down edges
  if (wv >= 1 && lane < 16){
    float* dst = rowbuf[(wv-1)*TILE_ + c];
    #pragma unroll
    for (int d=0; d<HID_; ++d) dst[d] = acc[d];
  }

  float d2R = 0.f;
  #pragma unroll
  for (int k=0; k<HID_/4; ++k){
    float t0 = acc[4*k]   - __shfl_down(acc[4*k],  1);
    float t1 = acc[4*k+1] - __shfl_down(acc[4*k+1],1);
    float t2 = acc[4*k+2] - __shfl_down(acc[4*k+2],1);
    float t3 = acc[4*k+3] - __shfl_down(acc[4*k+3],1);
    d2R += t0*t0 + t1*t1 + t2*t2 + t3*t3;
  }
  float d2D = 0.f;
  #pragma unroll
  for (int k=0; k<HID_/4; ++k){
    float t0 = acc[4*k]   - __shfl_down(acc[4*k],  16);
    float t1 = acc[4*k+1] - __shfl_down(acc[4*k+1],16);
    float t2 = acc[4*k+2] - __shfl_down(acc[4*k+2],16);
    float t3 = acc[4*k+3] - __shfl_down(acc[4*k+3],16);
    d2D += t0*t0 + t1*t1 + t2*t2 + t3*t3;
  }
  __syncthreads();
  if (lane >= 48 && wv < 3){          // row 4wv+3: neighbor row in wave wv+1
    const float* nb = rowbuf[wv*TILE_ + c];
    d2D = 0.f;
    #pragma unroll
    for (int k=0; k<HID_/4; ++k){
      float t0 = acc[4*k]   - nb[4*k];
      float t1 = acc[4*k+1] - nb[4*k+1];
      float t2 = acc[4*k+2] - nb[4*k+2];
      float t3 = acc[4*k+3] - nb[4*k+3];
      d2D += t0*t0 + t1*t1 + t2*t2 + t3*t3;
    }
  }

  if (c < TILE_-1){
    unsigned key = fkey(expf(-d2R));
    atomicMax(mk+i,   pack_mk(1u, key, i+1));
    atomicMax(mk+i+1, pack_mk(1u, key, i));
  }
  if (r < TILE_-1){
    unsigned key = fkey(expf(-d2D));
    atomicMax(mk+i,     pack_mk(1u, key, i+W_));
    atomicMax(mk+i+W_,  pack_mk(1u, key, i));
  }
}

// cross-tile it0 edges: 8 images x {15 boundary cols x 256, 15 boundary rows x 256}
__global__ void k_bedge(const float* __restrict__ fsum,
                        unsigned long long* __restrict__ mk){
  int t = blockIdx.x*blockDim.x + threadIdx.x;
  if (t >= B_*2*15*256) return;
  int y  = t & 255;
  int k  = (t >> 8) % 15;
  int ty = (t >> 8) / 15;
  int b  = ty >> 1, tp = ty & 1;
  int i, j;
  if (tp == 0){ i = (b<<16) | (y<<8) | (16*k+15); j = i+1;  }
  else        { i = (b<<16) | ((16*k+15)<<8) | y; j = i+W_; }
  const float4* fa = (const float4*)(fsum + (size_t)i*HID_);
  const float4* fb = (const float4*)(fsum + (size_t)j*HID_);
  float d2 = 0.f;
  #pragma unroll
  for (int q=0; q<HID_/4; ++q){
    float4 va = fa[q], vb = fb[q];
    float t0 = va.x-vb.x, t1 = va.y-vb.y, t2 = va.z-vb.z, t3 = va.w-vb.w;
    d2 += t0*t0 + t1*t1 + t2*t2 + t3*t3;
  }
  unsigned key = fkey(expf(-d2));
  atomicMax(mk+i, pack_mk(1u, key, j));
  atomicMax(mk+j, pack_mk(1u, key, i));
}

// mid-iteration fused sim+best, 1 px/thread, XCD-swizzled. Corner dedup:
// when right and down edges lead to the SAME neighbor region, the sim/key
// and atomics are identical -> compute once.
__global__ void k_simbest(const int* __restrict__ labels,
                          const float* __restrict__ fsum, const float* __restrict__ cnt,
                          unsigned long long* __restrict__ mk, unsigned tag,
                          const int* __restrict__ mflag){
  if (mflag[tag-1] == 0) return;     // tag>=2 always (loop starts at it=1)
  int i = swz2048(blockIdx.x)*256 + threadIdx.x;
  int rem = i & (HW_-1); int h = rem >> 8; int w = rem & (W_-1);
  int ri = labels[i];
  int rR = (w < W_-1) ? labels[i+1]  : ri;
  int rD = (h < H_-1) ? labels[i+W_] : ri;
  bool eR = (rR != ri), eD = (rD != ri) && (rD != rR);   // dedup corner case
  if (!eR && !eD) return;
  float rci = 1.0f / cnt[ri];
  const float4* fi = (const float4*)(fsum + (size_t)ri*HID_);
  float4 mi[HID_/4];
  #pragma unroll
  for (int k=0; k<HID_/4; ++k){
    float4 v = fi[k];
    mi[k] = make_float4(v.x*rci, v.y*rci, v.z*rci, v.w*rci);
  }
  if (eR){
    float rcj = 1.0f / cnt[rR];
    const float4* fj = (const float4*)(fsum + (size_t)rR*HID_);
    float d2 = 0.f;
    #pragma unroll
    for (int k=0; k<HID_/4; ++k){
      float4 v = fj[k];
      float tx = mi[k].x - v.x*rcj; float ty = mi[k].y - v.y*rcj;
      float tz = mi[k].z - v.z*rcj; float tw = mi[k].w - v.w*rcj;
      d2 += tx*tx + ty*ty + tz*tz + tw*tw;
    }
    unsigned key = fkey(expf(-d2));
    atomicMax(mk+ri, pack_mk(tag, key, rR));
    atomicMax(mk+rR, pack_mk(tag, key, ri));
  }
  if (eD){
    float rcj = 1.0f / cnt[rD];
    const float4* fj = (const float4*)(fsum + (size_t)rD*HID_);
    float d2 = 0.f;
    #pragma unroll
    for (int k=0; k<HID_/4; ++k){
      float4 v = fj[k];
      float tx = mi[k].x - v.x*rcj; float ty = mi[k].y - v.y*rcj;
      float tz = mi[k].z - v.z*rcj; float tw = mi[k].w - v.w*rcj;
      d2 += tx*tx + ty*ty + tz*tz + tw*tw;
    }
    unsigned key = fkey(expf(-d2));
    atomicMax(mk+ri, pack_mk(tag, key, rD));
    atomicMax(mk+rD, pack_mk(tag, key, ri));
  }
}

// chase + fold + relabel, 1 px/thread, XCD-swizzled. first=1 (it0): labels
// is uninitialized, l==i by construction. labels write-back is CONDITIONAL:
// converged pixels don't dirty their cache lines (saves HBM write drain in
// late passes). Sets mflag[tag] on any fold; early-exit when previous
// iteration was merge-free.
__global__ void k_update(const unsigned long long* __restrict__ mk, unsigned tag,
                         int* __restrict__ labels,
                         float* __restrict__ fsum, float* __restrict__ psum,
                         float* __restrict__ cnt, int* __restrict__ mflag,
                         int first){
  if (tag >= 2 && mflag[tag-1] == 0) return;
  int i = swz2048(blockIdx.x)*256 + threadIdx.x;
  int l = first ? i : labels[i];
  int x = l;
  for (int it = 0; it < (1<<20); ++it){
    int p = parent_dec(mk[x], tag, x);
    if (p == x) break;
    int pp = parent_dec(mk[p], tag, p);
    if (pp == x && x < p) break;     // broken 2-cycle: x is the root
    x = p;
  }
  if (l == i && x != i){             // dying root: fold into surviving root
    mflag[tag] = 1;
    atomicAdd(cnt+x, cnt[i]);
    const float* s = fsum + (size_t)i*HID_;
    float* ds = fsum + (size_t)x*HID_;
    #pragma unroll
    for (int d=0; d<HID_; ++d) atomicAdd(ds+d, s[d]);
    const float* ps = psum + (size_t)i*C_;
    float* dp = psum + (size_t)x*C_;
    #pragma unroll
    for (int cc=0; cc<C_; ++cc) atomicAdd(dp+cc, ps[cc]);
  }
  if (first || x != l) labels[i] = x;
}

// region features at roots only: rf3[l] = Linear(fsum[l]/cnt) - psum[l]/cnt,
// padded to float4 so k_out gathers one dwordx4. Every value l appearing in
// labels satisfies labels[l]==l, so all needed slots are written.
__global__ __launch_bounds__(256) void k_rf3(const int* __restrict__ labels,
      const float* __restrict__ cnt, const float* __restrict__ fsum,
      const float* __restrict__ psum, const float* __restrict__ lw,
      const float* __restrict__ lb, float4* __restrict__ rf3){
  __shared__ float lw_s[C_*HID_];
  __shared__ float lb_s[C_];
  for (int t = threadIdx.x; t < C_*HID_; t += blockDim.x) lw_s[t] = lw[t];
  if (threadIdx.x < C_) lb_s[threadIdx.x] = lb[threadIdx.x];
  __syncthreads();
  int i = swz2048(blockIdx.x)*256 + threadIdx.x;
  if (labels[i] != i) return;        // roots only
  float rc = 1.0f / cnt[i];
  const float* s = fsum + (size_t)i*HID_;
  float rf[C_];
  #pragma unroll
  for (int cc=0; cc<C_; ++cc){
    float a = 0.f;
    const float* wv = lw_s + cc*HID_;
    #pragma unroll
    for (int d=0; d<HID_; ++d) a += (s[d]*rc)*wv[d];
    rf[cc] = (a + lb_s[cc]) - psum[(size_t)i*C_+cc]*rc;
  }
  rf3[i] = make_float4(rf[0], rf[1], rf[2], 0.f);
}

// finalize: one 16B rf3 gather per pixel (wave-broadcast for uniform regions),
// mean injection, labels as float.
__global__ __launch_bounds__(256) void k_out(const int* __restrict__ labels,
      const float* __restrict__ img, const float4* __restrict__ rf3,
      float* __restrict__ out, float* __restrict__ outlab){
  int i = swz2048(blockIdx.x)*256 + threadIdx.x;
  int l = labels[i];
  float4 rf = rf3[l];
  int b = i >> 16; int rem = i & (HW_-1);
  const float* ip = img + (size_t)b*C_*HW_ + rem;
  out[(size_t)i*C_+0] = ip[0]             + rf.x;
  out[(size_t)i*C_+1] = ip[(size_t)HW_]   + rf.y;
  out[(size_t)i*C_+2] = ip[(size_t)2*HW_] + rf.z;
  outlab[i] = (float)l;
}

extern "C" void kernel_launch(void* const* d_in, const int* in_sizes, int n_in,
                              void* d_out, int out_size, void* d_ws, size_t ws_size,
                              hipStream_t stream) {
  const float* img = (const float*)d_in[0];
  const float* cw  = (const float*)d_in[1];
  const float* cb  = (const float*)d_in[2];
  const float* lw  = (const float*)d_in[3];
  const float* lb  = (const float*)d_in[4];

  char* ws = (char*)d_ws;
  size_t off = 0;
  auto alloc = [&](size_t bytes) -> void* {
    void* p = ws + off; off += (bytes + 255) & ~(size_t)255; return p;
  };
  float*              fsum   = (float*)              alloc((size_t)N_*HID_*4);
  float*              psum   = (float*)              alloc((size_t)N_*C_*4);
  float*              cnt    = (float*)              alloc((size_t)N_*4);
  unsigned long long* mk     = (unsigned long long*) alloc((size_t)N_*8);
  int*                labels = (int*)                alloc((size_t)N_*4);
  float4*             rf3    = (float4*)             alloc((size_t)N_*16);
  int*                mflag  = (int*)                alloc(64);

  dim3 blk(256);
  const int gN = 2048;

  k_conv_init<<<gN, blk, 0, stream>>>(img, cw, cb, fsum, cnt, psum, mk, mflag);
  k_bedge<<<240, blk, 0, stream>>>(fsum, mk);
  k_update<<<gN, blk, 0, stream>>>(mk, 1u, labels, fsum, psum, cnt, mflag, 1);

  for (int it = 1; it < 8; ++it) {
    k_simbest<<<gN, blk, 0, stream>>>(labels, fsum, cnt, mk, (unsigned)(it+1), mflag);
    k_update<<<gN, blk, 0, stream>>>(mk, (unsigned)(it+1), labels, fsum, psum, cnt, mflag, 0);
  }

  k_rf3<<<gN, blk, 0, stream>>>(labels, cnt, fsum, psum, lw, lb, rf3);

  float* out = (float*)d_out;
  k_out<<<gN, blk, 0, stream>>>(labels, img, rf3, out, out + (size_t)N_*C_);
}